// Round 10
// baseline (136.804 us; speedup 1.0000x reference)
//
#include <hip/hip_runtime.h>

typedef __attribute__((ext_vector_type(8))) short bf16x8;
typedef __attribute__((ext_vector_type(4))) float f32x4;

#define FROW   4224                    // 66 cols * 64 B per LDS feature row
#define FBUF   42240                   // 10 rows
#define BGRP   36864                   // 9 taps * 4096 B
#define LDS_TOT (2 * FBUF + 2 * BGRP)  // 158208 B

static __device__ __forceinline__ unsigned short f2bf(float f) {
  union { float f; unsigned u; } v; v.f = f;
  unsigned r = v.u + 0x7fffu + ((v.u >> 16) & 1u);
  return (unsigned short)(r >> 16);
}

static __device__ __forceinline__ void gload16(const void* g, void* l) {
  __builtin_amdgcn_global_load_lds(
      (const __attribute__((address_space(1))) void*)g,
      (__attribute__((address_space(3))) void*)l, 16, 0, 0);
}

// ---------------- kernel P: pack weights ----------------
// wpk: [it(126 = c2*9+tap)][co(64)][slot(4)][8ci] bf16,
// slot' = slot ^ ((co>>1)&3); unswizzled slot q holds ci = half*32 + q*8 + e.
__global__ void pack_w_k(const float* __restrict__ sb, const float* __restrict__ ss,
                         const float* __restrict__ cf, unsigned short* __restrict__ wpk) {
  int idx = blockIdx.x * 256 + threadIdx.x;
  if (idx >= 126 * 64 * 32) return;
  int e = idx & 7;
  int q = (idx >> 3) & 3;
  int co = (idx >> 5) & 63;
  int rest = idx >> 11;          // 0..1133
  int tap = rest % 9;
  int c2 = rest / 9;             // 0..13
  int c = c2 >> 1, half = c2 & 1;
  int ci = half * 32 + q * 8 + e;
  int kh = tap / 3, kw = tap % 3;
  int wi = ((co * 64 + ci) * 3 + kh) * 3 + kw;   // [co][ci][kh][kw]
  float v;
  if (c == 0) {
    v = sb[wi];
  } else {
    int s = (c - 1) / 3, g = (c - 1) % 3;        // s: 0=cos 1=sin
    v = cf[(s * 36864 + wi) * 3 + g] * ss[wi];
  }
  wpk[((c2 * 9 + tap) * 64 + co) * 32 + ((q ^ ((co >> 1) & 3)) << 3) + e] = f2bf(v);
}

// ---------------- kernel G: fused feature-gen + implicit GEMM ----------------
// grid (32 b, 8 hg) = 256 blocks = 1/CU. 8 waves, 2 K-groups (tap-split),
// wave = 128 px x 64 co. Per chunk (c,half): features computed IN-KERNEL from x
// (one feature c per chunk) into the swizzled LDS layout; B staged from wpk.
__global__ __launch_bounds__(512, 2) void gemm_k(
    const float* __restrict__ x, const unsigned short* __restrict__ wpk,
    const float* __restrict__ bias, float* __restrict__ out) {
  extern __shared__ __align__(16) char smem[];
  const int b = blockIdx.x;
  const int h0 = blockIdx.y * 8;
  const int tid = threadIdx.x;
  const int lane = tid & 63;
  const int wid = tid >> 6;
  const int l15 = lane & 15;
  const int lg = lane >> 4;
  const int grp = wid >> 2;          // 0: taps 0-4, 1: taps 5-8
  const int rowb = (wid & 3) * 2;    // wave's first image row within block
  const char* wpkB = (const char*)wpk;

  // FEATGEN thread map: w = tid&63 (lane=w: coalesced x loads), wave wid;
  // ci-quad rotates with w-octet to spread LDS write banks.
  const int fw = tid & 63;
  const int fkq = (wid + (fw >> 3)) & 7;        // ci-quad 0..7 (ci_l = 4*fkq+j)
  const int fcol = fw + 1;                      // LDS col (halo at 0/65)
  const int fslot = ((fkq >> 1) ^ ((fcol >> 1) & 3));
  const int foff = fcol * 64 + fslot * 16 + (fkq & 1) * 8;  // byte off within row

  // zero bytes never staged: halo cols + out-of-range rows (both feature buffers)
  for (int i = tid; i < 2 * FBUF / 4; i += 512) {
    int off = i * 4;
    int off2 = (off >= FBUF) ? off - FBUF : off;
    int row = off2 / FROW;
    int cb = off2 - row * FROW;
    int hh = h0 - 1 + row;
    bool staged = ((unsigned)hh < 64u) && (cb >= 64) && (cb < 4160);
    if (!staged) ((int*)smem)[i] = 0;
  }

  // precomputed swizzled LDS offsets for the tap loop
  int aoff[4][3], boff[4];
#pragma unroll
  for (int cf = 0; cf < 4; ++cf) {
#pragma unroll
    for (int kw = 0; kw < 3; ++kw) {
      int col = cf * 16 + l15 + kw;
      aoff[cf][kw] = col * 64 + ((lg ^ ((col >> 1) & 3)) << 4);
    }
    int co = cf * 16 + l15;
    boff[cf] = co * 64 + ((lg ^ ((co >> 1) & 3)) << 4);
  }

  // B staging: 36 gload16 per chunk spread over 8 waves
#define STAGE_B(cn, bdst)                                                        \
  for (int u = wid; u < 36; u += 8) {                                            \
    gload16(wpkB + (size_t)((cn) * 9 + (u >> 2)) * 4096 + (u & 3) * 1024 +       \
                lane * 16,                                                       \
            (bdst) + (u >> 2) * 4096 + (u & 3) * 1024);                          \
  }

  // Feature generation for chunk cn into fdst: 10 rows, 4 ci per thread.
#define FEATGEN(cn, fdst)                                                        \
  {                                                                              \
    const int c_ = (cn) >> 1, half_ = (cn) & 1;                                  \
    const float kf_ = (float)(c_ <= 3 ? c_ : c_ - 3);                            \
    const float* xb_ = x + (((size_t)b * 64 + half_ * 32 + 4 * fkq) * 64) * 64 + fw; \
    float xv[10][4];                                                             \
    _Pragma("unroll")                                                            \
    for (int r = 0; r < 10; ++r) {                                               \
      int hh = h0 - 1 + r;                                                       \
      if ((unsigned)hh < 64u) {                                                  \
        _Pragma("unroll")                                                        \
        for (int j = 0; j < 4; ++j) xv[r][j] = xb_[((size_t)j * 64 + hh) * 64];  \
      }                                                                          \
    }                                                                            \
    _Pragma("unroll")                                                            \
    for (int r = 0; r < 10; ++r) {                                               \
      int hh = h0 - 1 + r;                                                       \
      if ((unsigned)hh < 64u) {                                                  \
        unsigned long long pk = 0;                                               \
        _Pragma("unroll")                                                        \
        for (int j = 0; j < 4; ++j) {                                            \
          float v = xv[r][j], val;                                               \
          if (c_ == 0)      val = v / (1.0f + __expf(-v));                       \
          else if (c_ <= 3) val = __cosf(kf_ * v);                               \
          else              val = __sinf(kf_ * v);                               \
          pk |= (unsigned long long)f2bf(val) << (16 * j);                       \
        }                                                                        \
        *(unsigned long long*)((fdst) + r * FROW + foff) = pk;                   \
      }                                                                          \
    }                                                                            \
  }

  FEATGEN(0, smem)
  STAGE_B(0, smem + 2 * FBUF)
  __syncthreads();

  f32x4 acc[2][4][4];
#pragma unroll
  for (int ro = 0; ro < 2; ++ro)
#pragma unroll
    for (int cfi = 0; cfi < 4; ++cfi)
#pragma unroll
      for (int nf = 0; nf < 4; ++nf)
#pragma unroll
        for (int qq = 0; qq < 4; ++qq) acc[ro][cfi][nf][qq] = 0.0f;

#define LOADT(T, Ar, Br)                                                         \
  {                                                                              \
    const int kh_ = (T) / 3, kw_ = (T) % 3;                                      \
    const char* r0 = f + (rowb + kh_) * FROW;                                    \
    const char* r1 = r0 + FROW;                                                  \
    _Pragma("unroll")                                                            \
    for (int cfi = 0; cfi < 4; ++cfi) {                                          \
      Ar[0][cfi] = *(const bf16x8*)(r0 + aoff[cfi][kw_]);                        \
      Ar[1][cfi] = *(const bf16x8*)(r1 + aoff[cfi][kw_]);                        \
    }                                                                            \
    _Pragma("unroll")                                                            \
    for (int nf = 0; nf < 4; ++nf)                                               \
      Br[nf] = *(const bf16x8*)(bgc + (T) * 4096 + boff[nf]);                    \
  }
#define MFMAT(Ar, Br)                                                            \
  {                                                                              \
    _Pragma("unroll")                                                            \
    for (int ro = 0; ro < 2; ++ro)                                               \
      _Pragma("unroll")                                                          \
      for (int cfi = 0; cfi < 4; ++cfi)                                          \
        _Pragma("unroll")                                                        \
        for (int nf = 0; nf < 4; ++nf)                                           \
          acc[ro][cfi][nf] = __builtin_amdgcn_mfma_f32_16x16x32_bf16(            \
              Ar[ro][cfi], Br[nf], acc[ro][cfi][nf], 0, 0, 0);                   \
  }
#define SGB(m, n) __builtin_amdgcn_sched_group_barrier((m), (n), 0);

  for (int c2 = 0; c2 < 14; ++c2) {
    const int cur = c2 & 1;
    const char* f = smem + (cur ? FBUF : 0);
    const char* bgc = smem + 2 * FBUF + (cur ? BGRP : 0);
    if (c2 < 13) {
      char* fnext = smem + (cur ? 0 : FBUF);
      char* bnext = smem + 2 * FBUF + (cur ? 0 : BGRP);
      STAGE_B(c2 + 1, bnext)
      FEATGEN(c2 + 1, fnext)
    }
    bf16x8 Aa[2][4], Ab[2][4], Ba[4], Bb[4];
    if (grp == 0) {
      LOADT(0, Aa, Ba)
      LOADT(1, Ab, Bb)
      MFMAT(Aa, Ba)          // tap 0
      LOADT(2, Aa, Ba)
      MFMAT(Ab, Bb)          // tap 1
      LOADT(3, Ab, Bb)
      MFMAT(Aa, Ba)          // tap 2
      LOADT(4, Aa, Ba)
      MFMAT(Ab, Bb)          // tap 3
      MFMAT(Aa, Ba)          // tap 4
      SGB(0x100, 12)
#pragma unroll
      for (int g = 0; g < 16; ++g) { SGB(0x8, 8) SGB(0x100, 3) }
#pragma unroll
      for (int g = 0; g < 4; ++g) { SGB(0x8, 8) }
    } else {
      LOADT(5, Aa, Ba)
      LOADT(6, Ab, Bb)
      MFMAT(Aa, Ba)          // tap 5
      LOADT(7, Aa, Ba)
      MFMAT(Ab, Bb)          // tap 6
      LOADT(8, Ab, Bb)
      MFMAT(Aa, Ba)          // tap 7
      MFMAT(Ab, Bb)          // tap 8
      SGB(0x100, 12)
#pragma unroll
      for (int g = 0; g < 12; ++g) { SGB(0x8, 8) SGB(0x100, 3) }
#pragma unroll
      for (int g = 0; g < 4; ++g) { SGB(0x8, 8) }
    }
    __syncthreads();
  }
#undef SGB
#undef LOADT
#undef MFMAT
#undef STAGE_B
#undef FEATGEN

  // cross-group reduction: partials in LDS as [co(64)][pxl(512)] f32, px-XOR
  // swizzled by (co&7)<<2 (uniform 8 lanes per 16B slot -> conflict-free).
  if (grp == 1) {
#pragma unroll
    for (int ro = 0; ro < 2; ++ro)
#pragma unroll
      for (int cfi = 0; cfi < 4; ++cfi)
#pragma unroll
        for (int nf = 0; nf < 4; ++nf) {
          int co = nf * 16 + l15;
          int pxl = (rowb + ro) * 64 + cfi * 16 + (lg << 2);
          float* p = (float*)smem + co * 512 + (pxl ^ ((co & 7) << 2));
          *(f32x4*)p = acc[ro][cfi][nf];
        }
  }
  __syncthreads();
  if (grp == 0) {
#pragma unroll
    for (int ro = 0; ro < 2; ++ro) {
      const int h = h0 + rowb + ro;
#pragma unroll
      for (int cfi = 0; cfi < 4; ++cfi) {
        int w4 = cfi * 16 + (lg << 2);
#pragma unroll
        for (int nf = 0; nf < 4; ++nf) {
          int co = nf * 16 + l15;
          int pxl = (rowb + ro) * 64 + cfi * 16 + (lg << 2);
          const float* p = (const float*)smem + co * 512 + (pxl ^ ((co & 7) << 2));
          f32x4 part = *(const f32x4*)p;
          float bv = bias[co];
          f32x4 v = acc[ro][cfi][nf];
          f32x4 res;
          res[0] = v[0] + part[0] + bv;
          res[1] = v[1] + part[1] + bv;
          res[2] = v[2] + part[2] + bv;
          res[3] = v[3] + part[3] + bv;
          *(f32x4*)(out + ((size_t)(b * 64 + co) * 64 + h) * 64 + w4) = res;
        }
      }
    }
  }
}

// ---------------- fallback: naive fp32 direct (if ws too small) ----------------
__global__ void naive_k(const float* __restrict__ x, const float* __restrict__ sb,
                        const float* __restrict__ ss, const float* __restrict__ cf,
                        const float* __restrict__ bias, float* __restrict__ out) {
  int idx = blockIdx.x * 256 + threadIdx.x;
  if (idx >= 32 * 64 * 64 * 64) return;
  int w = idx & 63, h = (idx >> 6) & 63, co = (idx >> 12) & 63, b = idx >> 18;
  float acc = bias[co];
  for (int ci = 0; ci < 64; ++ci) {
    for (int kh = 0; kh < 3; ++kh) {
      int hh = h + kh - 1;
      if ((unsigned)hh >= 64u) continue;
      for (int kw = 0; kw < 3; ++kw) {
        int ww = w + kw - 1;
        if ((unsigned)ww >= 64u) continue;
        float v = x[((b * 64 + ci) * 64 + hh) * 64 + ww];
        int wi = ((co * 64 + ci) * 3 + kh) * 3 + kw;
        float s1, c1; __sincosf(v, &s1, &c1);
        float c2 = c1 * c1 - s1 * s1, s2 = 2.f * s1 * c1;
        float c3 = c1 * c2 - s1 * s2, s3 = s1 * c2 + c1 * s2;
        float t = sb[wi] * (v / (1.f + __expf(-v)));
        t += ss[wi] * (cf[wi * 3] * c1 + cf[wi * 3 + 1] * c2 + cf[wi * 3 + 2] * c3 +
                       cf[(36864 + wi) * 3] * s1 + cf[(36864 + wi) * 3 + 1] * s2 +
                       cf[(36864 + wi) * 3 + 2] * s3);
        acc += t;
      }
    }
  }
  out[idx] = acc;
}

extern "C" void kernel_launch(void* const* d_in, const int* in_sizes, int n_in,
                              void* d_out, int out_size, void* d_ws, size_t ws_size,
                              hipStream_t stream) {
  const float* x = (const float*)d_in[0];
  const float* sb = (const float*)d_in[1];
  const float* ss = (const float*)d_in[2];
  const float* cf = (const float*)d_in[3];
  const float* bias = (const float*)d_in[4];
  float* out = (float*)d_out;

  const size_t NEED = 1u << 20;   // only wpk (516 KB) lives in d_ws now
  if (ws_size >= NEED) {
    unsigned short* wpk = (unsigned short*)d_ws;
    pack_w_k<<<1008, 256, 0, stream>>>(sb, ss, cf, wpk);
    (void)hipFuncSetAttribute((const void*)gemm_k,
                              hipFuncAttributeMaxDynamicSharedMemorySize, LDS_TOT);
    gemm_k<<<dim3(32, 8), 512, LDS_TOT, stream>>>(x, wpk, bias, out);
  } else {
    naive_k<<<32768, 256, 0, stream>>>(x, sb, ss, cf, bias, out);
  }
}

// Round 11
// 100.123 us; speedup vs baseline: 1.3664x; 1.3664x over previous
//
#include <hip/hip_runtime.h>

typedef __attribute__((ext_vector_type(8))) short bf16x8;
typedef __attribute__((ext_vector_type(4))) float f32x4;
typedef __attribute__((ext_vector_type(16))) float f32x16;

#define FROW   4224                    // 66 cols * 64 B per LDS feature row
#define FBUF   42240                   // 10 rows
#define BGRP   36864                   // 9 taps * 4096 B
#define LDS_TOT (2 * FBUF + 2 * BGRP)  // 158208 B

static __device__ __forceinline__ unsigned short f2bf(float f) {
  union { float f; unsigned u; } v; v.f = f;
  unsigned r = v.u + 0x7fffu + ((v.u >> 16) & 1u);
  return (unsigned short)(r >> 16);
}

static __device__ __forceinline__ void gload16(const void* g, void* l) {
  __builtin_amdgcn_global_load_lds(
      (const __attribute__((address_space(1))) void*)g,
      (__attribute__((address_space(3))) void*)l, 16, 0, 0);
}

// ---------------- kernel F: feature expansion + fused weight pack ----------------
// fg: [c2(14)][b(32)][h(64)][w(64)][slot(4)][8ci] bf16 (4096 B per (c2,b,h) row),
// slot' = slot ^ (((w+1)>>1)&3)  (LDS col = w+1 after halo shift; same key as read)
// wpk: [it(126 = c2*9+tap)][co(64)][slot(4)][8ci] bf16, slot' = slot ^ ((co>>1)&3).
// Pack work (258048 items) folded in: each of the 2048 blocks packs 126 items.
__global__ void feats_k(const float* __restrict__ x, const float* __restrict__ sb,
                        const float* __restrict__ ss, const float* __restrict__ cf,
                        unsigned short* __restrict__ fg, unsigned short* __restrict__ wpk) {
  __shared__ __align__(16) unsigned short lds[64 * 456]; // [w][c(7)][8 slots][8], stride padded
  const int b = blockIdx.x, h = blockIdx.y;
  const int tid = threadIdx.x;             // 256
  const int w = tid & 63, cig = tid >> 6;  // 4 groups x 16 ci
  const int key = ((w + 1) >> 1) & 3;
  const int base = w * 456;
#pragma unroll
  for (int i = 0; i < 16; ++i) {
    int ci = cig * 16 + i;
    float v = x[(((size_t)b * 64 + ci) * 64 + h) * 64 + w];
    float sg = 1.0f / (1.0f + __expf(-v));
    float f0 = v * sg;
    float s1, c1;
    __sincosf(v, &s1, &c1);
    float c2v = c1 * c1 - s1 * s1, s2v = 2.0f * s1 * c1;
    float c3v = c1 * c2v - s1 * s2v, s3v = s1 * c2v + c1 * s2v;
    int q = ci >> 3;                 // 0..7
    int half = q >> 2, qq = q & 3;
    int sl = (half * 4 + (qq ^ key)) * 8 + (ci & 7);
    lds[base + 0 * 64 + sl] = f2bf(f0);
    lds[base + 1 * 64 + sl] = f2bf(c1);
    lds[base + 2 * 64 + sl] = f2bf(c2v);
    lds[base + 3 * 64 + sl] = f2bf(c3v);
    lds[base + 4 * 64 + sl] = f2bf(s1);
    lds[base + 5 * 64 + sl] = f2bf(s2v);
    lds[base + 6 * 64 + sl] = f2bf(s3v);
  }
  __syncthreads();
#pragma unroll
  for (int k = 0; k < 14; ++k) {
    int u = tid + k * 256;         // [c2(14)][w(64)][qs(4)]
    int qs = u & 3;
    int ww = (u >> 2) & 63;
    int c2i = u >> 8;
    int cc = c2i >> 1, half = c2i & 1;
    uint4 v = *(const uint4*)&lds[ww * 456 + cc * 64 + (half * 4 + qs) * 8];
    unsigned short* dst = fg + ((size_t)(c2i * 32 + b) * 64 + h) * 2048 + (ww * 4 + qs) * 8;
    *(uint4*)dst = v;
  }
  // fused weight pack: this block handles items [blk*126, blk*126+126)
  if (tid < 126) {
    int idx = (b * 64 + h) * 126 + tid;
    int e = idx & 7;
    int q = (idx >> 3) & 3;
    int co = (idx >> 5) & 63;
    int rest = idx >> 11;          // 0..1133
    int tap = rest % 9;
    int c2p = rest / 9;            // 0..13
    int c = c2p >> 1, half = c2p & 1;
    int ci = half * 32 + q * 8 + e;
    int kh = tap / 3, kw = tap % 3;
    int wi = ((co * 64 + ci) * 3 + kh) * 3 + kw;   // [co][ci][kh][kw]
    float v;
    if (c == 0) {
      v = sb[wi];
    } else {
      int s = (c - 1) / 3, g = (c - 1) % 3;        // s: 0=cos 1=sin
      v = cf[(s * 36864 + wi) * 3 + g] * ss[wi];
    }
    wpk[((c2p * 9 + tap) * 64 + co) * 32 + ((q ^ ((co >> 1) & 3)) << 3) + e] = f2bf(v);
  }
}

// ---------------- kernel G: implicit GEMM (32x32x16 MFMA, no setprio) ----------------
// grid (32 b, 8 hg) = 256 blocks = 1/CU. 8 waves in 2 K-groups (tap-split):
// waves 0-3 taps 0-4, waves 4-7 taps 5-8 (each SIMD hosts one wave of each).
// Wave: M=128 px (2 image rows) x 64 cout, acc[ro2][wf2][nf2] f32x16 = 128 VGPR.
__global__ __launch_bounds__(512, 2) void gemm_k(
    const unsigned short* __restrict__ fg, const unsigned short* __restrict__ wpk,
    const float* __restrict__ bias, float* __restrict__ out) {
  extern __shared__ __align__(16) char smem[];
  const int b = blockIdx.x;
  const int h0 = blockIdx.y * 8;
  const int tid = threadIdx.x;
  const int lane = tid & 63;
  const int wid = tid >> 6;
  const int l31 = lane & 31;
  const int lh = lane >> 5;          // 0/1: k-half within slot pair
  const int grp = wid >> 2;          // 0: taps 0-4, 1: taps 5-8
  const int rowb = (wid & 3) * 2;    // wave's first image row within block
  const char* fgB = (const char*)fg;
  const char* wpkB = (const char*)wpk;

  // zero bytes never staged: halo cols + out-of-range rows (both feature buffers)
  for (int i = tid; i < 2 * FBUF / 4; i += 512) {
    int off = i * 4;
    int off2 = (off >= FBUF) ? off - FBUF : off;
    int row = off2 / FROW;
    int cb = off2 - row * FROW;
    int hh = h0 - 1 + row;
    bool staged = ((unsigned)hh < 64u) && (cb >= 64) && (cb < 4160);
    if (!staged) ((int*)smem)[i] = 0;
  }

  // hoisted swizzled LDS offsets: A[wf][kw][ks], B[nf][ks]
  int aoff[2][3][2], boff[2][2];
#pragma unroll
  for (int wf = 0; wf < 2; ++wf)
#pragma unroll
    for (int kw = 0; kw < 3; ++kw) {
      int col = wf * 32 + l31 + kw;
#pragma unroll
      for (int ks = 0; ks < 2; ++ks)
        aoff[wf][kw][ks] = col * 64 + (((ks * 2 + lh) ^ ((col >> 1) & 3)) << 4);
    }
#pragma unroll
  for (int nf = 0; nf < 2; ++nf) {
    int co = nf * 32 + l31;
#pragma unroll
    for (int ks = 0; ks < 2; ++ks)
      boff[nf][ks] = co * 64 + (((ks * 2 + lh) ^ ((co >> 1) & 3)) << 4);
  }

  // staging helper: u 0..39 = feature row/quarter, 40..75 = B tap/part
#define STAGE_GRP(cn, fdst, bdst)                                                \
  for (int u = wid; u < 76; u += 8) {                                            \
    if (u < 40) {                                                                \
      int row = u >> 2, j = u & 3;                                               \
      int hh = h0 - 1 + row;                                                     \
      if ((unsigned)hh < 64u)                                                    \
        gload16(fgB + ((size_t)((cn) * 2048 + b * 64 + hh)) * 4096 +             \
                    j * 1024 + lane * 16,                                        \
                (fdst) + row * FROW + 64 + j * 1024);                            \
    } else {                                                                     \
      int t = u - 40;                                                            \
      int tap = t >> 2, part = t & 3;                                            \
      gload16(wpkB + (size_t)((cn) * 9 + tap) * 4096 + part * 1024 + lane * 16,  \
              (bdst) + tap * 4096 + part * 1024);                                \
    }                                                                            \
  }

  STAGE_GRP(0, smem, smem + 2 * FBUF);
  __syncthreads();

  f32x16 acc[2][2][2];
#pragma unroll
  for (int ro = 0; ro < 2; ++ro)
#pragma unroll
    for (int wf = 0; wf < 2; ++wf)
#pragma unroll
      for (int nf = 0; nf < 2; ++nf)
#pragma unroll
        for (int qq = 0; qq < 16; ++qq) acc[ro][wf][nf][qq] = 0.0f;

#define COMP_TAP(T)                                                              \
  {                                                                              \
    const int kh_ = (T) / 3, kw_ = (T) % 3;                                      \
    const char* r0 = f + (rowb + kh_) * FROW;                                    \
    const char* r1 = r0 + FROW;                                                  \
    bf16x8 A[2][2][2], Bv[2][2];                                                 \
    _Pragma("unroll")                                                            \
    for (int wf = 0; wf < 2; ++wf)                                               \
      _Pragma("unroll")                                                          \
      for (int ks = 0; ks < 2; ++ks) {                                           \
        A[0][wf][ks] = *(const bf16x8*)(r0 + aoff[wf][kw_][ks]);                 \
        A[1][wf][ks] = *(const bf16x8*)(r1 + aoff[wf][kw_][ks]);                 \
      }                                                                          \
    _Pragma("unroll")                                                            \
    for (int nf = 0; nf < 2; ++nf)                                               \
      _Pragma("unroll")                                                          \
      for (int ks = 0; ks < 2; ++ks)                                             \
        Bv[nf][ks] = *(const bf16x8*)(bgc + (T) * 4096 + boff[nf][ks]);          \
    _Pragma("unroll")                                                            \
    for (int ro = 0; ro < 2; ++ro)                                               \
      _Pragma("unroll")                                                          \
      for (int wf = 0; wf < 2; ++wf)                                             \
        _Pragma("unroll")                                                        \
        for (int nf = 0; nf < 2; ++nf)                                           \
          _Pragma("unroll")                                                      \
          for (int ks = 0; ks < 2; ++ks)                                         \
            acc[ro][wf][nf] = __builtin_amdgcn_mfma_f32_32x32x16_bf16(           \
                A[ro][wf][ks], Bv[nf][ks], acc[ro][wf][nf], 0, 0, 0);            \
  }

  for (int c2 = 0; c2 < 14; ++c2) {
    const int cur = c2 & 1;
    const char* f = smem + (cur ? FBUF : 0);
    const char* bgc = smem + 2 * FBUF + (cur ? BGRP : 0);
    if (c2 < 13) {
      char* fnext = smem + (cur ? 0 : FBUF);
      char* bnext = smem + 2 * FBUF + (cur ? 0 : BGRP);
      STAGE_GRP(c2 + 1, fnext, bnext);
    }
    if (grp == 0) {
      COMP_TAP(0) COMP_TAP(1) COMP_TAP(2) COMP_TAP(3) COMP_TAP(4)
    } else {
      COMP_TAP(5) COMP_TAP(6) COMP_TAP(7) COMP_TAP(8)
    }
    __syncthreads();
  }
#undef COMP_TAP
#undef STAGE_GRP

  // cross-group reduction: partials in LDS as [co(64)][pxl(512)] f32,
  // px-XOR swizzled by ((co&7)<<2).
  if (grp == 1) {
#pragma unroll
    for (int ro = 0; ro < 2; ++ro)
#pragma unroll
      for (int wf = 0; wf < 2; ++wf)
#pragma unroll
        for (int nf = 0; nf < 2; ++nf) {
          int co = nf * 32 + l31;
#pragma unroll
          for (int j = 0; j < 4; ++j) {
            int px = (rowb + ro) * 64 + wf * 32 + j * 8 + (lh << 2);
            float* p = (float*)smem + co * 512 + (px ^ ((co & 7) << 2));
            f32x4 v;
            v[0] = acc[ro][wf][nf][4 * j + 0];
            v[1] = acc[ro][wf][nf][4 * j + 1];
            v[2] = acc[ro][wf][nf][4 * j + 2];
            v[3] = acc[ro][wf][nf][4 * j + 3];
            *(f32x4*)p = v;
          }
        }
  }
  __syncthreads();
  if (grp == 0) {
#pragma unroll
    for (int ro = 0; ro < 2; ++ro) {
      const int h = h0 + rowb + ro;
#pragma unroll
      for (int wf = 0; wf < 2; ++wf)
#pragma unroll
        for (int nf = 0; nf < 2; ++nf) {
          int co = nf * 32 + l31;
          float bv = bias[co];
#pragma unroll
          for (int j = 0; j < 4; ++j) {
            int w4 = wf * 32 + j * 8 + (lh << 2);
            int px = (rowb + ro) * 64 + w4;
            const float* p = (const float*)smem + co * 512 + (px ^ ((co & 7) << 2));
            f32x4 part = *(const f32x4*)p;
            f32x4 res;
            res[0] = acc[ro][wf][nf][4 * j + 0] + part[0] + bv;
            res[1] = acc[ro][wf][nf][4 * j + 1] + part[1] + bv;
            res[2] = acc[ro][wf][nf][4 * j + 2] + part[2] + bv;
            res[3] = acc[ro][wf][nf][4 * j + 3] + part[3] + bv;
            *(f32x4*)(out + ((size_t)(b * 64 + co) * 64 + h) * 64 + w4) = res;
          }
        }
    }
  }
}

// ---------------- fallback: naive fp32 direct (if ws too small) ----------------
__global__ void naive_k(const float* __restrict__ x, const float* __restrict__ sb,
                        const float* __restrict__ ss, const float* __restrict__ cf,
                        const float* __restrict__ bias, float* __restrict__ out) {
  int idx = blockIdx.x * 256 + threadIdx.x;
  if (idx >= 32 * 64 * 64 * 64) return;
  int w = idx & 63, h = (idx >> 6) & 63, co = (idx >> 12) & 63, b = idx >> 18;
  float acc = bias[co];
  for (int ci = 0; ci < 64; ++ci) {
    for (int kh = 0; kh < 3; ++kh) {
      int hh = h + kh - 1;
      if ((unsigned)hh >= 64u) continue;
      for (int kw = 0; kw < 3; ++kw) {
        int ww = w + kw - 1;
        if ((unsigned)ww >= 64u) continue;
        float v = x[((b * 64 + ci) * 64 + hh) * 64 + ww];
        int wi = ((co * 64 + ci) * 3 + kh) * 3 + kw;
        float s1, c1; __sincosf(v, &s1, &c1);
        float c2 = c1 * c1 - s1 * s1, s2 = 2.f * s1 * c1;
        float c3 = c1 * c2 - s1 * s2, s3 = s1 * c2 + c1 * s2;
        float t = sb[wi] * (v / (1.f + __expf(-v)));
        t += ss[wi] * (cf[wi * 3] * c1 + cf[wi * 3 + 1] * c2 + cf[wi * 3 + 2] * c3 +
                       cf[(36864 + wi) * 3] * s1 + cf[(36864 + wi) * 3 + 1] * s2 +
                       cf[(36864 + wi) * 3 + 2] * s3);
        acc += t;
      }
    }
  }
  out[idx] = acc;
}

extern "C" void kernel_launch(void* const* d_in, const int* in_sizes, int n_in,
                              void* d_out, int out_size, void* d_ws, size_t ws_size,
                              hipStream_t stream) {
  const float* x = (const float*)d_in[0];
  const float* sb = (const float*)d_in[1];
  const float* ss = (const float*)d_in[2];
  const float* cf = (const float*)d_in[3];
  const float* bias = (const float*)d_in[4];
  float* out = (float*)d_out;

  const size_t FEATS_OFF = 1u << 20;                          // wpk in first 1 MB
  const size_t NEED = FEATS_OFF + (size_t)14 * 32 * 64 * 4096; // ~118.5 MB
  if (ws_size >= NEED) {
    unsigned short* wpk = (unsigned short*)d_ws;
    unsigned short* fg = (unsigned short*)((char*)d_ws + FEATS_OFF);
    feats_k<<<dim3(32, 64), 256, 0, stream>>>(x, sb, ss, cf, fg, wpk);
    (void)hipFuncSetAttribute((const void*)gemm_k,
                              hipFuncAttributeMaxDynamicSharedMemorySize, LDS_TOT);
    gemm_k<<<dim3(32, 8), 512, LDS_TOT, stream>>>(fg, wpk, bias, out);
  } else {
    naive_k<<<32768, 256, 0, stream>>>(x, sb, ss, cf, bias, out);
  }
}

// Round 12
// 92.106 us; speedup vs baseline: 1.4853x; 1.0870x over previous
//
#include <hip/hip_runtime.h>

typedef __attribute__((ext_vector_type(8))) short bf16x8;
typedef __attribute__((ext_vector_type(4))) float f32x4;

#define FROW   4224                     // 66 cols * 64 B per LDS feature row
#define FBUF4  25344                    // 6 rows (4-row block + halo)
#define BTRIO  12288                    // 3 taps * 4096 B
#define LDS_T2 (2 * FBUF4 + 2 * BTRIO)  // 75264 B -> 2 blocks/CU

static __device__ __forceinline__ unsigned short f2bf(float f) {
  union { float f; unsigned u; } v; v.f = f;
  unsigned r = v.u + 0x7fffu + ((v.u >> 16) & 1u);
  return (unsigned short)(r >> 16);
}

static __device__ __forceinline__ void gload16(const void* g, void* l) {
  __builtin_amdgcn_global_load_lds(
      (const __attribute__((address_space(1))) void*)g,
      (__attribute__((address_space(3))) void*)l, 16, 0, 0);
}

// ---------------- kernel F: feature expansion + fused weight pack ----------------
// fg: [c2(14)][b(32)][h(64)][w(64)][slot(4)][8ci] bf16, slot' = slot ^ (((w+1)>>1)&3)
// wpk: [it(126)][co(64)][slot(4)][8ci] bf16, slot' = slot ^ ((co>>1)&3)
__global__ void feats_k(const float* __restrict__ x, const float* __restrict__ sb,
                        const float* __restrict__ ss, const float* __restrict__ cf,
                        unsigned short* __restrict__ fg, unsigned short* __restrict__ wpk) {
  __shared__ __align__(16) unsigned short lds[64 * 456];
  const int b = blockIdx.x, h = blockIdx.y;
  const int tid = threadIdx.x;             // 256
  const int w = tid & 63, cig = tid >> 6;
  const int key = ((w + 1) >> 1) & 3;
  const int base = w * 456;
#pragma unroll
  for (int i = 0; i < 16; ++i) {
    int ci = cig * 16 + i;
    float v = x[(((size_t)b * 64 + ci) * 64 + h) * 64 + w];
    float sg = 1.0f / (1.0f + __expf(-v));
    float f0 = v * sg;
    float s1, c1;
    __sincosf(v, &s1, &c1);
    float c2v = c1 * c1 - s1 * s1, s2v = 2.0f * s1 * c1;
    float c3v = c1 * c2v - s1 * s2v, s3v = s1 * c2v + c1 * s2v;
    int q = ci >> 3;
    int half = q >> 2, qq = q & 3;
    int sl = (half * 4 + (qq ^ key)) * 8 + (ci & 7);
    lds[base + 0 * 64 + sl] = f2bf(f0);
    lds[base + 1 * 64 + sl] = f2bf(c1);
    lds[base + 2 * 64 + sl] = f2bf(c2v);
    lds[base + 3 * 64 + sl] = f2bf(c3v);
    lds[base + 4 * 64 + sl] = f2bf(s1);
    lds[base + 5 * 64 + sl] = f2bf(s2v);
    lds[base + 6 * 64 + sl] = f2bf(s3v);
  }
  __syncthreads();
#pragma unroll
  for (int k = 0; k < 14; ++k) {
    int u = tid + k * 256;
    int qs = u & 3;
    int ww = (u >> 2) & 63;
    int c2i = u >> 8;
    int cc = c2i >> 1, half = c2i & 1;
    uint4 v = *(const uint4*)&lds[ww * 456 + cc * 64 + (half * 4 + qs) * 8];
    unsigned short* dst = fg + ((size_t)(c2i * 32 + b) * 64 + h) * 2048 + (ww * 4 + qs) * 8;
    *(uint4*)dst = v;
  }
  if (tid < 126) {   // fused weight pack: 126 items per block
    int idx = (b * 64 + h) * 126 + tid;
    int e = idx & 7;
    int q = (idx >> 3) & 3;
    int co = (idx >> 5) & 63;
    int rest = idx >> 11;
    int tap = rest % 9;
    int c2p = rest / 9;
    int c = c2p >> 1, half = c2p & 1;
    int ci = half * 32 + q * 8 + e;
    int kh = tap / 3, kw = tap % 3;
    int wi = ((co * 64 + ci) * 3 + kh) * 3 + kw;
    float v;
    if (c == 0) {
      v = sb[wi];
    } else {
      int s = (c - 1) / 3, g = (c - 1) % 3;
      v = cf[(s * 36864 + wi) * 3 + g] * ss[wi];
    }
    wpk[((c2p * 9 + tap) * 64 + co) * 32 + ((q ^ ((co >> 1) & 3)) << 3) + e] = f2bf(v);
  }
}

// ---------------- kernel G: implicit GEMM, 2 blocks/CU TLP ----------------
// grid (32 b, 16 hg) = 512 blocks = 2/CU (LDS 75.3 KB). 4 waves/block; wave wid
// owns image row h0+wid: M=64 px x N=64 co, ALL 9 taps (acc is final, no
// reduction). Barrier per kh-trio (42/kernel); B staged as 3-tap trios,
// features double-buffered per chunk, staging spread across the 3 kh phases.
__global__ __launch_bounds__(256, 2) void gemm_k(
    const unsigned short* __restrict__ fg, const unsigned short* __restrict__ wpk,
    const float* __restrict__ bias, float* __restrict__ out) {
  extern __shared__ __align__(16) char smem[];
  const int b = blockIdx.x;
  const int h0 = blockIdx.y * 4;
  const int tid = threadIdx.x;
  const int lane = tid & 63;
  const int wid = tid >> 6;          // 0..3
  const int l15 = lane & 15;
  const int lg = lane >> 4;
  const char* fgB = (const char*)fg;
  const char* wpkB = (const char*)wpk;

  // zero never-staged bytes: halo cols + out-of-range rows (both feat buffers)
  for (int i = tid; i < 2 * FBUF4 / 4; i += 256) {
    int off = i * 4;
    int off2 = (off >= FBUF4) ? off - FBUF4 : off;
    int row = off2 / FROW;
    int cb = off2 - row * FROW;
    int hh = h0 - 1 + row;
    bool staged = ((unsigned)hh < 64u) && (cb >= 64) && (cb < 4160);
    if (!staged) ((int*)smem)[i] = 0;
  }

  // hoisted swizzled LDS offsets
  int aoff[4][3], boff[4];
#pragma unroll
  for (int cf = 0; cf < 4; ++cf) {
#pragma unroll
    for (int kw = 0; kw < 3; ++kw) {
      int col = cf * 16 + l15 + kw;
      aoff[cf][kw] = col * 64 + ((lg ^ ((col >> 1) & 3)) << 4);
    }
    int co = cf * 16 + l15;
    boff[cf] = co * 64 + ((lg ^ ((co >> 1) & 3)) << 4);
  }

  // stage B trio for (chunk cn, kh khn) into bdst: 12 gload16 over 4 waves
#define STAGE_TRIO(cn, khn, bdst)                                                \
  _Pragma("unroll")                                                              \
  for (int i = 0; i < 3; ++i) {                                                  \
    int u = i * 4 + wid;             /* 0..11: tap t=u>>2, part=u&3 */           \
    gload16(wpkB + (size_t)((cn) * 9 + (khn) * 3 + (u >> 2)) * 4096 +            \
                (u & 3) * 1024 + lane * 16,                                      \
            (bdst) + (u >> 2) * 4096 + (u & 3) * 1024);                          \
  }
  // stage 8 of 24 feature calls (rows 0..5 x 4 parts) for chunk cn, phase kh
#define STAGE_F8(cn, khp, fdst)                                                  \
  _Pragma("unroll")                                                              \
  for (int j = 0; j < 2; ++j) {                                                  \
    int k = (khp) * 8 + wid * 2 + j;  /* 0..23 */                                \
    int row = k >> 2, part = k & 3;                                              \
    int hh = h0 - 1 + row;                                                       \
    if ((unsigned)hh < 64u)                                                      \
      gload16(fgB + ((size_t)((cn) * 2048 + b * 64 + hh)) * 4096 +               \
                  part * 1024 + lane * 16,                                       \
              (fdst) + row * FROW + 64 + part * 1024);                           \
  }

  // prologue: feat chunk 0 (all 24) + B trio (0,0)
#pragma unroll
  for (int p = 0; p < 3; ++p) { STAGE_F8(0, p, smem) }
  STAGE_TRIO(0, 0, smem + 2 * FBUF4)
  __syncthreads();

  f32x4 acc[4][4];
#pragma unroll
  for (int cfi = 0; cfi < 4; ++cfi)
#pragma unroll
    for (int nf = 0; nf < 4; ++nf)
#pragma unroll
      for (int qq = 0; qq < 4; ++qq) acc[cfi][nf][qq] = 0.0f;

  for (int c2 = 0; c2 < 14; ++c2) {
    const char* f = smem + ((c2 & 1) ? FBUF4 : 0);
    char* fnext = smem + (((c2 + 1) & 1) ? FBUF4 : 0);
#pragma unroll
    for (int kh = 0; kh < 3; ++kh) {
      const int khg = c2 * 3 + kh;
      const char* bb = smem + 2 * FBUF4 + ((khg & 1) ? BTRIO : 0);
      // stage next B trio
      if (khg < 41) {
        char* bnext = smem + 2 * FBUF4 + (((khg + 1) & 1) ? BTRIO : 0);
        const int cn = (khg + 1) / 3, khn = (khg + 1) % 3;
        STAGE_TRIO(cn, khn, bnext)
      }
      // stage 8 feature calls for next chunk
      if (c2 < 13) { STAGE_F8(c2 + 1, kh, fnext) }

      const char* frow = f + (wid + kh) * FROW;
#pragma unroll
      for (int kw = 0; kw < 3; ++kw) {
        bf16x8 A[4], Bv[4];
#pragma unroll
        for (int cfi = 0; cfi < 4; ++cfi)
          A[cfi] = *(const bf16x8*)(frow + aoff[cfi][kw]);
#pragma unroll
        for (int nf = 0; nf < 4; ++nf)
          Bv[nf] = *(const bf16x8*)(bb + kw * 4096 + boff[nf]);
#pragma unroll
        for (int cfi = 0; cfi < 4; ++cfi)
#pragma unroll
          for (int nf = 0; nf < 4; ++nf)
            acc[cfi][nf] = __builtin_amdgcn_mfma_f32_16x16x32_bf16(
                A[cfi], Bv[nf], acc[cfi][nf], 0, 0, 0);
      }
      __syncthreads();
    }
  }
#undef STAGE_TRIO
#undef STAGE_F8

  // epilogue: direct store (wave owns full K). C/D: col(l15)=co, row=lg*4+reg=w
  const int h = h0 + wid;
#pragma unroll
  for (int cfi = 0; cfi < 4; ++cfi) {
    int w4 = cfi * 16 + (lg << 2);
#pragma unroll
    for (int nf = 0; nf < 4; ++nf) {
      int co = nf * 16 + l15;
      float bv = bias[co];
      f32x4 v = acc[cfi][nf];
      f32x4 res;
      res[0] = v[0] + bv; res[1] = v[1] + bv; res[2] = v[2] + bv; res[3] = v[3] + bv;
      *(f32x4*)(out + ((size_t)(b * 64 + co) * 64 + h) * 64 + w4) = res;
    }
  }
}

// ---------------- fallback: naive fp32 direct (if ws too small) ----------------
__global__ void naive_k(const float* __restrict__ x, const float* __restrict__ sb,
                        const float* __restrict__ ss, const float* __restrict__ cf,
                        const float* __restrict__ bias, float* __restrict__ out) {
  int idx = blockIdx.x * 256 + threadIdx.x;
  if (idx >= 32 * 64 * 64 * 64) return;
  int w = idx & 63, h = (idx >> 6) & 63, co = (idx >> 12) & 63, b = idx >> 18;
  float acc = bias[co];
  for (int ci = 0; ci < 64; ++ci) {
    for (int kh = 0; kh < 3; ++kh) {
      int hh = h + kh - 1;
      if ((unsigned)hh >= 64u) continue;
      for (int kw = 0; kw < 3; ++kw) {
        int ww = w + kw - 1;
        if ((unsigned)ww >= 64u) continue;
        float v = x[((b * 64 + ci) * 64 + hh) * 64 + ww];
        int wi = ((co * 64 + ci) * 3 + kh) * 3 + kw;
        float s1, c1; __sincosf(v, &s1, &c1);
        float c2 = c1 * c1 - s1 * s1, s2 = 2.f * s1 * c1;
        float c3 = c1 * c2 - s1 * s2, s3 = s1 * c2 + c1 * s2;
        float t = sb[wi] * (v / (1.f + __expf(-v)));
        t += ss[wi] * (cf[wi * 3] * c1 + cf[wi * 3 + 1] * c2 + cf[wi * 3 + 2] * c3 +
                       cf[(36864 + wi) * 3] * s1 + cf[(36864 + wi) * 3 + 1] * s2 +
                       cf[(36864 + wi) * 3 + 2] * s3);
        acc += t;
      }
    }
  }
  out[idx] = acc;
}

extern "C" void kernel_launch(void* const* d_in, const int* in_sizes, int n_in,
                              void* d_out, int out_size, void* d_ws, size_t ws_size,
                              hipStream_t stream) {
  const float* x = (const float*)d_in[0];
  const float* sb = (const float*)d_in[1];
  const float* ss = (const float*)d_in[2];
  const float* cf = (const float*)d_in[3];
  const float* bias = (const float*)d_in[4];
  float* out = (float*)d_out;

  const size_t FEATS_OFF = 1u << 20;                          // wpk in first 1 MB
  const size_t NEED = FEATS_OFF + (size_t)14 * 32 * 64 * 4096; // ~118.5 MB
  if (ws_size >= NEED) {
    unsigned short* wpk = (unsigned short*)d_ws;
    unsigned short* fg = (unsigned short*)((char*)d_ws + FEATS_OFF);
    feats_k<<<dim3(32, 64), 256, 0, stream>>>(x, sb, ss, cf, fg, wpk);
    (void)hipFuncSetAttribute((const void*)gemm_k,
                              hipFuncAttributeMaxDynamicSharedMemorySize, LDS_T2);
    gemm_k<<<dim3(32, 16), 256, LDS_T2, stream>>>(fg, wpk, bias, out);
  } else {
    naive_k<<<32768, 256, 0, stream>>>(x, sb, ss, cf, bias, out);
  }
}